// Round 1
// baseline (742.936 us; speedup 1.0000x reference)
//
#include <hip/hip_runtime.h>

// EnhanceCls: 5x (GEMM->BN->leaky->GEMM->BN) + prototype enhancement (dist topk)
// + feature walk (cos/softmax/topk). C=5 S=5 Q=75 P=196 D=384 K=30.

#define CC 5
#define SS 5
#define QQ 75
#define PP 196
#define DD 384
#define KK 30

typedef short bf16x8 __attribute__((ext_vector_type(8)));
typedef float f32x4  __attribute__((ext_vector_type(4)));

__device__ __forceinline__ unsigned short f2bf(float f) {
    unsigned u = __float_as_uint(f);
    unsigned r = (u + 0x7fffu + ((u >> 16) & 1u)) >> 16;
    return (unsigned short)r;
}

__device__ __forceinline__ void lds_load16(const unsigned short* g, unsigned short* s) {
    __builtin_amdgcn_global_load_lds(
        (const __attribute__((address_space(1))) unsigned int*)g,
        (__attribute__((address_space(3))) unsigned int*)s, 16, 0, 0);
}

// ---- weight prep: Wt[n*384+k] = bf16(W[k*384+n]) ----
__global__ void prep_w(const float* __restrict__ W, unsigned short* __restrict__ Wt) {
    int idx = blockIdx.x * 256 + threadIdx.x;      // 147456 total
    int n = idx / DD, k = idx - n * DD;
    Wt[idx] = f2bf(W[k * DD + n]);
}

// ---- f32 -> bf16 with zero row padding ----
__global__ void conv_k(const float* __restrict__ src, unsigned short* __restrict__ dst, int M) {
    int idx = blockIdx.x * 256 + threadIdx.x;
    int row = idx / DD;
    dst[idx] = (row < M) ? f2bf(src[idx]) : (unsigned short)0;
}

// ---- bf16 GEMM: H[Mpad x 384] = A[Mpad x 384] * B[384 x 384], Bt is B^T (n-major) ----
// 128x128 tile, BK=64, 4 waves, global_load_lds w/ both-sides XOR chunk swizzle.
__global__ __launch_bounds__(256) void gemm_k(const unsigned short* __restrict__ A,
                                              const unsigned short* __restrict__ Bt,
                                              float* __restrict__ H) {
    __shared__ __align__(16) unsigned short As[128 * 64];
    __shared__ __align__(16) unsigned short Bs[128 * 64];
    const int tid = threadIdx.x;
    const int w = tid >> 6, l = tid & 63;
    const int wr = w >> 1, wc = w & 1;
    const int m0 = blockIdx.x * 128, n0 = blockIdx.y * 128;

    f32x4 acc[4][4];
#pragma unroll
    for (int i = 0; i < 4; ++i)
#pragma unroll
        for (int j = 0; j < 4; ++j) acc[i][j] = f32x4{0.f, 0.f, 0.f, 0.f};

    int rowg[4], kpg[4];
#pragma unroll
    for (int i = 0; i < 4; ++i) {
        int c = (i * 4096 + w * 1024 + l * 16) >> 4;  // 16B chunk index
        int row = c >> 3, kp = c & 7;
        rowg[i] = row;
        kpg[i] = kp ^ (row & 7);   // pre-swizzled global chunk (rule #21: both sides)
    }

    for (int kt = 0; kt < 6; ++kt) {
        const int k0 = kt * 64;
#pragma unroll
        for (int i = 0; i < 4; ++i) {
            lds_load16(A  + (size_t)(m0 + rowg[i]) * DD + k0 + kpg[i] * 8, &As[i * 2048 + w * 512]);
            lds_load16(Bt + (size_t)(n0 + rowg[i]) * DD + k0 + kpg[i] * 8, &Bs[i * 2048 + w * 512]);
        }
        __syncthreads();
#pragma unroll
        for (int ks = 0; ks < 2; ++ks) {
            bf16x8 af[4], bg[4];
#pragma unroll
            for (int i = 0; i < 4; ++i) {
                int rm = wr * 64 + i * 16 + (l & 15);
                af[i] = *(const bf16x8*)&As[rm * 64 + (((ks << 2) + (l >> 4)) ^ (rm & 7)) * 8];
                int rn = wc * 64 + i * 16 + (l & 15);
                bg[i] = *(const bf16x8*)&Bs[rn * 64 + (((ks << 2) + (l >> 4)) ^ (rn & 7)) * 8];
            }
#pragma unroll
            for (int i = 0; i < 4; ++i)
#pragma unroll
                for (int j = 0; j < 4; ++j)
                    acc[i][j] = __builtin_amdgcn_mfma_f32_16x16x32_bf16(af[i], bg[j], acc[i][j], 0, 0, 0);
        }
        __syncthreads();
    }
    // C/D layout: col = lane&15, row = (lane>>4)*4 + reg  [m89-verified]
#pragma unroll
    for (int i = 0; i < 4; ++i) {
        int rb = m0 + wr * 64 + i * 16 + ((l >> 4) << 2);
#pragma unroll
        for (int j = 0; j < 4; ++j) {
            int col = n0 + wc * 64 + j * 16 + (l & 15);
#pragma unroll
            for (int r = 0; r < 4; ++r)
                H[(size_t)(rb + r) * DD + col] = acc[i][j][r];
        }
    }
}

// ---- column stats, stage 1: partial sums over 128-row slabs (deterministic) ----
__global__ void colstats(const float* __restrict__ H, float* __restrict__ partial, int M) {
    int t = threadIdx.x;                  // 384 threads, one column each
    int r0 = blockIdx.x * 128;
    int rend = min(M, r0 + 128);
    float s = 0.f, s2 = 0.f;
    for (int r = r0; r < rend; ++r) {
        float v = H[(size_t)r * DD + t];
        s += v; s2 += v * v;
    }
    partial[blockIdx.x * 768 + t] = s;
    partial[blockIdx.x * 768 + 384 + t] = s2;
}

// ---- column stats, stage 2: mean + invstd ----
__global__ void colfin(const float* __restrict__ partial, int nblk, float invM,
                       float* __restrict__ mstats) {
    int t = threadIdx.x;  // 384
    float s = 0.f, s2 = 0.f;
    for (int b = 0; b < nblk; ++b) { s += partial[b * 768 + t]; s2 += partial[b * 768 + 384 + t]; }
    float m = s * invM;
    float var = fmaxf(s2 * invM - m * m, 0.f);
    mstats[t] = m;
    mstats[384 + t] = rsqrtf(var + 1e-5f);
}

// ---- BN + leaky-relu -> bf16 (pad rows -> 0) ----
__global__ void act_k(const float* __restrict__ H, const float* __restrict__ mstats,
                      const float* __restrict__ g, const float* __restrict__ be,
                      const float* __restrict__ alp, unsigned short* __restrict__ A2, int M) {
    int idx = blockIdx.x * 256 + threadIdx.x;
    int row = idx / DD, col = idx - row * DD;
    float o = 0.f;
    if (row < M) {
        float v = (H[idx] - mstats[col]) * mstats[384 + col] * g[col] + be[col];
        float al = *alp;
        o = (v >= 0.f) ? v : al * v;
    }
    A2[idx] = f2bf(o);
}

// ---- final BN (+ optional residual) -> f32 out (+ optional bf16 copy); pad rows -> 0 ----
__global__ void mlp_out_k(const float* __restrict__ H, const float* __restrict__ mstats,
                          const float* __restrict__ g, const float* __restrict__ be,
                          const float* __restrict__ res, float* __restrict__ outf,
                          unsigned short* __restrict__ outb, int M) {
    int idx = blockIdx.x * 256 + threadIdx.x;
    int row = idx / DD, col = idx - row * DD;
    float v = 0.f;
    if (row < M) {
        v = (H[idx] - mstats[col]) * mstats[384 + col] * g[col] + be[col];
        if (res) v += res[idx];
    }
    outf[idx] = v;
    if (outb) outb[idx] = f2bf(v);
}

// ---- dist[b][cs][p] = ||cls[cs]-patch[cs,p]||  (2*25*196 blocks, 1 wave each) ----
__global__ void dist_k(const float* __restrict__ epsP, const float* __restrict__ dpfP,
                       const float* __restrict__ supC, const float* __restrict__ dsupC,
                       float* __restrict__ dist) {
    int id = blockIdx.x;               // 0..9799
    int b = id / (CC * SS * PP);
    int r = id - b * (CC * SS * PP);   // cs*196+p
    int cs = r / PP;
    const float* patch = b ? dpfP : epsP;
    const float* cls = b ? dsupC : supC;
    int l = threadIdx.x;  // 64
    const float* pr = patch + (size_t)r * DD;
    const float* cr = cls + (size_t)cs * DD;
    float s = 0.f;
    for (int d = l; d < DD; d += 64) { float df = cr[d] - pr[d]; s += df * df; }
#pragma unroll
    for (int off = 32; off > 0; off >>= 1) s += __shfl_xor(s, off);
    if (l == 0) dist[id] = sqrtf(s);
}

// ---- enhance: sim = dist/(other+1e-6), top-30 over p, mean of selected patches ----
__global__ void enh_k(const float* __restrict__ dist, const float* __restrict__ epsP,
                      const float* __restrict__ dpfP, const float* __restrict__ supC,
                      const float* __restrict__ dsupC, float* __restrict__ enh) {
    int id = blockIdx.x;          // 0..49 = b*25+cs
    int b = id / 25, cs = id - b * 25, c = cs / SS;
    int t = threadIdx.x;          // 384
    __shared__ float sim[PP];
    __shared__ int idxs[KK];
    const float* db = dist + b * (CC * SS * PP);
    if (t < PP) {
        float osum = 0.f;
        for (int cc = 0; cc < CC; ++cc) osum += db[cc * SS * PP + t];   // d0 rows (s=0)
        float other = osum - db[c * SS * PP + t];
        sim[t] = db[cs * PP + t] / (other + 1e-6f);
    }
    __syncthreads();
    for (int j = 0; j < KK; ++j) {
        if (t < 64) {
            float bv = -3.4e38f; int bi = 1 << 30;
            for (int p = t; p < PP; p += 64) {
                float v = sim[p];
                if (v > bv || (v == bv && p < bi)) { bv = v; bi = p; }
            }
#pragma unroll
            for (int off = 1; off < 64; off <<= 1) {
                float ov = __shfl_xor(bv, off); int oi = __shfl_xor(bi, off);
                if (ov > bv || (ov == bv && oi < bi)) { bv = ov; bi = oi; }
            }
            if (t == 0) { idxs[j] = bi; sim[bi] = -3.4e38f; }
        }
        __syncthreads();
    }
    const float* patch = b ? dpfP : epsP;
    const float* cls = b ? dsupC : supC;
    float sum = 0.f;
    for (int j = 0; j < KK; ++j) sum += patch[((size_t)cs * PP + idxs[j]) * DD + t];
    enh[(size_t)id * DD + t] = 2.f * cls[(size_t)cs * DD + t] + sum * (1.f / 30.f);
}

// ---- ep[c] = mean over 10 enh rows; also prototype norms ----
__global__ void ep_k(const float* __restrict__ enh, float* __restrict__ outEp,
                     float* __restrict__ npb) {
    int t = threadIdx.x;  // 384
    __shared__ float red[DD];
    for (int c = 0; c < CC; ++c) {
        float v = 0.f;
        for (int b = 0; b < 2; ++b)
            for (int s = 0; s < SS; ++s)
                v += enh[((b * 25) + (c * SS + s)) * DD + t];
        v *= 0.1f;
        outEp[c * DD + t] = v;
        red[t] = v * v;
        __syncthreads();
        if (t < 64) {
            float s = 0.f;
            for (int i = t; i < DD; i += 64) s += red[i];
#pragma unroll
            for (int off = 32; off > 0; off >>= 1) s += __shfl_xor(s, off);
            if (t == 0) npb[c] = sqrtf(s);
        }
        __syncthreads();
    }
}

// ---- feature walk: cos -> softmax -> top30 -> weighted sum ----
__global__ void walk_k(const float* __restrict__ epq, const float* __restrict__ qcls,
                       const float* __restrict__ ep, const float* __restrict__ npb,
                       float* __restrict__ outp) {
    int bid = blockIdx.x;         // c*75+q
    int c = bid / QQ, q = bid - c * QQ;
    int t = threadIdx.x;          // 256
    __shared__ __align__(16) float epl[DD];
    __shared__ float red[256];
    __shared__ float wv[PP];
    __shared__ float vals[KK];
    __shared__ int idxs[KK];
    epl[t] = ep[c * DD + t];
    if (t < DD - 256) epl[256 + t] = ep[c * DD + 256 + t];
    __syncthreads();
    float cosv = -3.4e38f;
    if (t < PP) {
        const float4* row = (const float4*)(epq + ((size_t)q * PP + t) * DD);
        const float4* e4 = (const float4*)epl;
        float dot = 0.f, nq = 0.f;
        for (int d4 = 0; d4 < DD / 4; ++d4) {
            float4 x = row[d4]; float4 e = e4[d4];
            dot += e.x * x.x + e.y * x.y + e.z * x.z + e.w * x.w;
            nq += x.x * x.x + x.y * x.y + x.z * x.z + x.w * x.w;
        }
        float den = fmaxf(npb[c] * sqrtf(nq), 1e-8f);
        cosv = dot / den;
    }
    red[t] = cosv; __syncthreads();
    for (int st = 128; st > 0; st >>= 1) { if (t < st) red[t] = fmaxf(red[t], red[t + st]); __syncthreads(); }
    float mx = red[0]; __syncthreads();
    float e = (t < PP) ? expf(cosv - mx) : 0.f;
    red[t] = e; __syncthreads();
    for (int st = 128; st > 0; st >>= 1) { if (t < st) red[t] += red[t + st]; __syncthreads(); }
    float inv = 1.f / red[0];
    __syncthreads();
    if (t < PP) wv[t] = e * inv;
    __syncthreads();
    for (int j = 0; j < KK; ++j) {
        if (t < 64) {
            float bv = -3.4e38f; int bi = 1 << 30;
            for (int p = t; p < PP; p += 64) {
                float v = wv[p];
                if (v > bv || (v == bv && p < bi)) { bv = v; bi = p; }
            }
#pragma unroll
            for (int off = 1; off < 64; off <<= 1) {
                float ov = __shfl_xor(bv, off); int oi = __shfl_xor(bi, off);
                if (ov > bv || (ov == bv && oi < bi)) { bv = ov; bi = oi; }
            }
            if (t == 0) { vals[j] = bv; idxs[j] = bi; wv[bi] = -3.4e38f; }
        }
        __syncthreads();
    }
    for (int d = t; d < DD; d += 256) {
        float a = 0.f;
        for (int j = 0; j < KK; ++j) a += vals[j] * epq[((size_t)q * PP + idxs[j]) * DD + d];
        outp[(size_t)bid * DD + d] = 2.f * qcls[q * DD + d] + a;
    }
}

extern "C" void kernel_launch(void* const* d_in, const int* in_sizes, int n_in,
                              void* d_out, int out_size, void* d_ws, size_t ws_size,
                              hipStream_t stream) {
    const float* sup   = (const float*)d_in[0];
    const float* qcls  = (const float*)d_in[1];
    const float* dsupI = (const float*)d_in[2];
    const float* epsI  = (const float*)d_in[3];
    const float* epqI  = (const float*)d_in[4];
    const float* dpI   = (const float*)d_in[5];
    const float* daW1 = (const float*)d_in[6],  *daG1 = (const float*)d_in[8],
               * daBe1 = (const float*)d_in[9], *daAl = (const float*)d_in[10];
    const float* daW2 = (const float*)d_in[11], *daG2 = (const float*)d_in[13],
               * daBe2 = (const float*)d_in[14];
    const float* paW1 = (const float*)d_in[15], *paG1 = (const float*)d_in[17],
               * paBe1 = (const float*)d_in[18], *paAl = (const float*)d_in[19];
    const float* paW2 = (const float*)d_in[20], *paG2 = (const float*)d_in[22],
               * paBe2 = (const float*)d_in[23];

    char* ws = (char*)d_ws;
    size_t off = 0;
    auto alloc = [&](size_t b) -> void* {
        void* p = ws + off;
        off = (off + b + 255) & ~(size_t)255;
        return p;
    };
    // padded row counts
    const int M_S = 25,    MP_S = 128;
    const int M_P = 4900,  MP_P = 4992;
    const int M_Q = 14700, MP_Q = 14720;

    unsigned short* wtDa1 = (unsigned short*)alloc(DD * DD * 2);
    unsigned short* wtDa2 = (unsigned short*)alloc(DD * DD * 2);
    unsigned short* wtPa1 = (unsigned short*)alloc(DD * DD * 2);
    unsigned short* wtPa2 = (unsigned short*)alloc(DD * DD * 2);
    unsigned short* xb    = (unsigned short*)alloc((size_t)MP_Q * DD * 2);
    float*          hbuf  = (float*)alloc((size_t)MP_Q * DD * 4);
    unsigned short* a2buf = (unsigned short*)alloc((size_t)MP_Q * DD * 2);
    float*          partial = (float*)alloc((size_t)116 * 768 * 4);
    float*          mstats  = (float*)alloc(768 * 4);
    float*          dalleSup = (float*)alloc((size_t)MP_S * DD * 4);
    float*          dp0   = (float*)alloc((size_t)MP_P * DD * 4);
    unsigned short* dp0b  = (unsigned short*)alloc((size_t)MP_P * DD * 2);
    float*          epsB  = (float*)alloc((size_t)MP_P * DD * 4);
    float*          epqB  = (float*)alloc((size_t)MP_Q * DD * 4);
    float*          dpfB  = (float*)alloc((size_t)MP_P * DD * 4);
    float*          distB = (float*)alloc((size_t)2 * CC * SS * PP * 4);
    float*          enhB  = (float*)alloc((size_t)50 * DD * 4);
    float*          npB   = (float*)alloc(64);

    auto run_mlp = [&](const unsigned short* x, int M, int Mpad,
                       const unsigned short* Wt1, const unsigned short* Wt2,
                       const float* g1, const float* be1, const float* alp,
                       const float* g2, const float* be2,
                       const float* res, float* outf, unsigned short* outb) {
        dim3 gg(Mpad / 128, 3);
        int nElem = Mpad * DD;
        int nblk = (M + 127) / 128;
        float invM = 1.0f / (float)M;
        gemm_k<<<gg, 256, 0, stream>>>(x, Wt1, hbuf);
        colstats<<<nblk, 384, 0, stream>>>(hbuf, partial, M);
        colfin<<<1, 384, 0, stream>>>(partial, nblk, invM, mstats);
        act_k<<<nElem / 256, 256, 0, stream>>>(hbuf, mstats, g1, be1, alp, a2buf, M);
        gemm_k<<<gg, 256, 0, stream>>>(a2buf, Wt2, hbuf);
        colstats<<<nblk, 384, 0, stream>>>(hbuf, partial, M);
        colfin<<<1, 384, 0, stream>>>(partial, nblk, invM, mstats);
        mlp_out_k<<<nElem / 256, 256, 0, stream>>>(hbuf, mstats, g2, be2, res, outf, outb, M);
    };

    // weights -> bf16 transposed
    prep_w<<<576, 256, 0, stream>>>(daW1, wtDa1);
    prep_w<<<576, 256, 0, stream>>>(daW2, wtDa2);
    prep_w<<<576, 256, 0, stream>>>(paW1, wtPa1);
    prep_w<<<576, 256, 0, stream>>>(paW2, wtPa2);

    // 1: dalle_sup = da_mlp(dalle_emb_support)
    conv_k<<<MP_S * DD / 256, 256, 0, stream>>>(dsupI, xb, M_S);
    run_mlp(xb, M_S, MP_S, wtDa1, wtDa2, daG1, daBe1, daAl, daG2, daBe2,
            nullptr, dalleSup, nullptr);
    // 2: dp0 = da_mlp(dalle_patch_embedding)  (+ bf16 copy for stage 5)
    conv_k<<<MP_P * DD / 256, 256, 0, stream>>>(dpI, xb, M_P);
    run_mlp(xb, M_P, MP_P, wtDa1, wtDa2, daG1, daBe1, daAl, daG2, daBe2,
            nullptr, dp0, dp0b);
    // 3: eps = emb_patch_support + pa_mlp(emb_patch_support)
    conv_k<<<MP_P * DD / 256, 256, 0, stream>>>(epsI, xb, M_P);
    run_mlp(xb, M_P, MP_P, wtPa1, wtPa2, paG1, paBe1, paAl, paG2, paBe2,
            epsI, epsB, nullptr);
    // 4: epq = emb_patch_query + pa_mlp(emb_patch_query)
    conv_k<<<MP_Q * DD / 256, 256, 0, stream>>>(epqI, xb, M_Q);
    run_mlp(xb, M_Q, MP_Q, wtPa1, wtPa2, paG1, paBe1, paAl, paG2, paBe2,
            epqI, epqB, nullptr);
    // 5: dalle_patch = dp0 + pa_mlp(dp0)
    run_mlp(dp0b, M_P, MP_P, wtPa1, wtPa2, paG1, paBe1, paAl, paG2, paBe2,
            dp0, dpfB, nullptr);

    // enhancement
    dist_k<<<2 * CC * SS * PP, 64, 0, stream>>>(epsB, dpfB, sup, dalleSup, distB);
    enh_k<<<2 * CC * SS, 384, 0, stream>>>(distB, epsB, dpfB, sup, dalleSup, enhB);

    float* outEp = (float*)d_out;
    float* outW = (float*)d_out + CC * DD;
    ep_k<<<1, 384, 0, stream>>>(enhB, outEp, npB);
    walk_k<<<CC * QQ, 256, 0, stream>>>(epqB, qcls, outEp, npB, outW);
}

// Round 2
// 366.524 us; speedup vs baseline: 2.0270x; 2.0270x over previous
//
#include <hip/hip_runtime.h>

// EnhanceCls: 3 segmented MLP passes (GEMM+fused BN-stats) + prototype
// enhancement + feature walk (coalesced cos + per-(c,q) softmax/topk).
// C=5 S=5 Q=75 P=196 D=384 K=30.

#define CC 5
#define SS 5
#define QQ 75
#define PP 196
#define DD 384
#define KK 30
#define QP (QQ * PP)   // 14700

typedef short bf16x8 __attribute__((ext_vector_type(8)));
typedef float f32x4  __attribute__((ext_vector_type(4)));

struct SegDesc { int b0, b1; float invM; };

__device__ __forceinline__ unsigned short f2bf(float f) {
    unsigned u = __float_as_uint(f);
    unsigned r = (u + 0x7fffu + ((u >> 16) & 1u)) >> 16;
    return (unsigned short)r;
}

__device__ __forceinline__ void lds_load16(const unsigned short* g, unsigned short* s) {
    __builtin_amdgcn_global_load_lds(
        (const __attribute__((address_space(1))) unsigned int*)g,
        (__attribute__((address_space(3))) unsigned int*)s, 16, 0, 0);
}

// ---- weight prep: 4 matrices, Wt[m][n*384+k] = bf16(W[m][k*384+n]) ----
__global__ void prep_w4(const float* __restrict__ W0, const float* __restrict__ W1,
                        const float* __restrict__ W2, const float* __restrict__ W3,
                        unsigned short* __restrict__ Wt) {
    int idx = blockIdx.x * 256 + threadIdx.x;      // 4 * 147456
    int m = idx / (DD * DD);
    int rem = idx - m * (DD * DD);
    int n = rem / DD, k = rem - n * DD;
    const float* W = (m == 0) ? W0 : (m == 1) ? W1 : (m == 2) ? W2 : W3;
    Wt[idx] = f2bf(W[k * DD + n]);
}

// ---- 2-segment f32 -> bf16 with zero row padding ----
__global__ void conv2_k(const float* __restrict__ src0, int M0, int Mp0,
                        const float* __restrict__ src1, int M1,
                        unsigned short* __restrict__ dst) {
    int idx = blockIdx.x * 256 + threadIdx.x;
    int row = idx / DD, col = idx - row * DD;
    float v = 0.f;
    if (row < Mp0) {
        if (row < M0) v = src0[(size_t)row * DD + col];
    } else {
        int r1 = row - Mp0;
        if (r1 < M1) v = src1[(size_t)r1 * DD + col];
    }
    dst[idx] = f2bf(v);
}

// ---- bf16 GEMM: H[Mpad x 384] = A[Mpad x 384] * B[384 x 384] (Bt = B^T), plus
// fused per-block column stats partial[mb][col][{sum,sumsq}] (pad rows are 0). ----
__global__ __launch_bounds__(256) void gemm_k(const unsigned short* __restrict__ A,
                                              const unsigned short* __restrict__ Bt,
                                              float* __restrict__ H,
                                              float* __restrict__ partial) {
    __shared__ __align__(16) unsigned short As[128 * 64];
    __shared__ __align__(16) unsigned short Bs[128 * 64];
    __shared__ float sred[2][2][64][2];
    const int tid = threadIdx.x;
    const int w = tid >> 6, l = tid & 63;
    const int wr = w >> 1, wc = w & 1;
    const int m0 = blockIdx.x * 128, n0 = blockIdx.y * 128;

    f32x4 acc[4][4];
#pragma unroll
    for (int i = 0; i < 4; ++i)
#pragma unroll
        for (int j = 0; j < 4; ++j) acc[i][j] = f32x4{0.f, 0.f, 0.f, 0.f};

    int rowg[4], kpg[4];
#pragma unroll
    for (int i = 0; i < 4; ++i) {
        int c = (i * 4096 + w * 1024 + l * 16) >> 4;  // 16B chunk index
        int row = c >> 3, kp = c & 7;
        rowg[i] = row;
        kpg[i] = kp ^ (row & 7);   // pre-swizzled global chunk (both-sides rule)
    }

    for (int kt = 0; kt < 6; ++kt) {
        const int k0 = kt * 64;
#pragma unroll
        for (int i = 0; i < 4; ++i) {
            lds_load16(A  + (size_t)(m0 + rowg[i]) * DD + k0 + kpg[i] * 8, &As[i * 2048 + w * 512]);
            lds_load16(Bt + (size_t)(n0 + rowg[i]) * DD + k0 + kpg[i] * 8, &Bs[i * 2048 + w * 512]);
        }
        __syncthreads();
#pragma unroll
        for (int ks = 0; ks < 2; ++ks) {
            bf16x8 af[4], bg[4];
#pragma unroll
            for (int i = 0; i < 4; ++i) {
                int rm = wr * 64 + i * 16 + (l & 15);
                af[i] = *(const bf16x8*)&As[rm * 64 + (((ks << 2) + (l >> 4)) ^ (rm & 7)) * 8];
                int rn = wc * 64 + i * 16 + (l & 15);
                bg[i] = *(const bf16x8*)&Bs[rn * 64 + (((ks << 2) + (l >> 4)) ^ (rn & 7)) * 8];
            }
#pragma unroll
            for (int i = 0; i < 4; ++i)
#pragma unroll
                for (int j = 0; j < 4; ++j)
                    acc[i][j] = __builtin_amdgcn_mfma_f32_16x16x32_bf16(af[i], bg[j], acc[i][j], 0, 0, 0);
        }
        __syncthreads();
    }
    // C/D layout: col = lane&15, row = (lane>>4)*4 + reg
#pragma unroll
    for (int i = 0; i < 4; ++i) {
        int rb = m0 + wr * 64 + i * 16 + ((l >> 4) << 2);
#pragma unroll
        for (int j = 0; j < 4; ++j) {
            int col = n0 + wc * 64 + j * 16 + (l & 15);
#pragma unroll
            for (int r = 0; r < 4; ++r)
                H[(size_t)(rb + r) * DD + col] = acc[i][j][r];
        }
    }
    // fused column stats over this block's 128 rows
    float ls[4], ls2[4];
#pragma unroll
    for (int j = 0; j < 4; ++j) { ls[j] = 0.f; ls2[j] = 0.f; }
#pragma unroll
    for (int i = 0; i < 4; ++i)
#pragma unroll
        for (int j = 0; j < 4; ++j)
#pragma unroll
            for (int r = 0; r < 4; ++r) {
                float v = acc[i][j][r];
                ls[j] += v; ls2[j] += v * v;
            }
#pragma unroll
    for (int j = 0; j < 4; ++j) {   // reduce across the 4 row-lane groups (l>>4)
        ls[j]  += __shfl_xor(ls[j], 16);  ls[j]  += __shfl_xor(ls[j], 32);
        ls2[j] += __shfl_xor(ls2[j], 16); ls2[j] += __shfl_xor(ls2[j], 32);
    }
    if ((l >> 4) == 0) {
#pragma unroll
        for (int j = 0; j < 4; ++j) {
            sred[wr][wc][j * 16 + (l & 15)][0] = ls[j];
            sred[wr][wc][j * 16 + (l & 15)][1] = ls2[j];
        }
    }
    __syncthreads();
    if (tid < 128) {
        int wcx = tid >> 6, c64 = tid & 63;
        float s  = sred[0][wcx][c64][0] + sred[1][wcx][c64][0];
        float s2 = sred[0][wcx][c64][1] + sred[1][wcx][c64][1];
        size_t pi = ((size_t)blockIdx.x * DD + n0 + tid) * 2;
        partial[pi] = s; partial[pi + 1] = s2;
    }
}

// ---- stats finalize per segment: grid = nseg blocks x 384 threads ----
__global__ void colfin(const float* __restrict__ partial, SegDesc s0, SegDesc s1,
                       float* __restrict__ mstats) {
    SegDesc sd = blockIdx.x ? s1 : s0;
    int t = threadIdx.x;  // 384
    float s = 0.f, s2 = 0.f;
    for (int b = sd.b0; b < sd.b1; ++b) {
        size_t pi = ((size_t)b * DD + t) * 2;
        s += partial[pi]; s2 += partial[pi + 1];
    }
    float m = s * sd.invM;
    float var = fmaxf(s2 * sd.invM - m * m, 0.f);
    mstats[blockIdx.x * 768 + t] = m;
    mstats[blockIdx.x * 768 + 384 + t] = rsqrtf(var + 1e-5f);
}

// ---- BN + leaky-relu -> bf16 (2 segments, pad rows -> 0) ----
__global__ void act_k(const float* __restrict__ H, const float* __restrict__ mstats,
                      const float* __restrict__ g, const float* __restrict__ be,
                      const float* __restrict__ alp, unsigned short* __restrict__ A2,
                      int Mp0, int M0, int M1) {
    int idx = blockIdx.x * 256 + threadIdx.x;
    int row = idx / DD, col = idx - row * DD;
    int seg = (row >= Mp0);
    int vr = seg ? row - Mp0 : row;
    int M = seg ? M1 : M0;
    float o = 0.f;
    if (vr < M) {
        const float* ms = mstats + seg * 768;
        float v = (H[idx] - ms[col]) * ms[384 + col] * g[col] + be[col];
        float al = *alp;
        o = (v >= 0.f) ? v : al * v;
    }
    A2[idx] = f2bf(o);
}

// ---- final BN (+ optional residual) per segment -> f32 out (+ optional bf16) ----
__global__ void mlp_out_k(const float* __restrict__ H, const float* __restrict__ mstats,
                          const float* __restrict__ g, const float* __restrict__ be,
                          const float* __restrict__ res0, float* __restrict__ out0f,
                          unsigned short* __restrict__ out0b,
                          const float* __restrict__ res1, float* __restrict__ out1f,
                          int Mp0, int M0, int M1) {
    int idx = blockIdx.x * 256 + threadIdx.x;
    int row = idx / DD, col = idx - row * DD;
    int seg = (row >= Mp0);
    int vr = seg ? row - Mp0 : row;
    int M = seg ? M1 : M0;
    const float* res = seg ? res1 : res0;
    float v = 0.f;
    if (vr < M) {
        const float* ms = mstats + seg * 768;
        v = (H[idx] - ms[col]) * ms[384 + col] * g[col] + be[col];
        if (res) v += res[(size_t)vr * DD + col];
    }
    size_t oi = (size_t)vr * DD + col;
    if (seg) {
        out1f[oi] = v;
    } else {
        out0f[oi] = v;
        if (out0b) out0b[oi] = f2bf(v);
    }
}

// ---- dist[b][cs][p] = ||cls[cs]-patch[cs,p]||  (2*25*196 blocks, 1 wave) ----
__global__ void dist_k(const float* __restrict__ epsP, const float* __restrict__ dpfP,
                       const float* __restrict__ supC, const float* __restrict__ dsupC,
                       float* __restrict__ dist) {
    int id = blockIdx.x;               // 0..9799
    int b = id / (CC * SS * PP);
    int r = id - b * (CC * SS * PP);   // cs*196+p
    int cs = r / PP;
    const float* patch = b ? dpfP : epsP;
    const float* cls = b ? dsupC : supC;
    int l = threadIdx.x;  // 64
    const float* pr = patch + (size_t)r * DD;
    const float* cr = cls + (size_t)cs * DD;
    float s = 0.f;
    for (int d = l; d < DD; d += 64) { float df = cr[d] - pr[d]; s += df * df; }
#pragma unroll
    for (int off = 32; off > 0; off >>= 1) s += __shfl_xor(s, off);
    if (l == 0) dist[id] = sqrtf(s);
}

// ---- enhance: sim = dist/(other+1e-6), top-30 over p, mean of selected ----
__global__ void enh_k(const float* __restrict__ dist, const float* __restrict__ epsP,
                      const float* __restrict__ dpfP, const float* __restrict__ supC,
                      const float* __restrict__ dsupC, float* __restrict__ enh) {
    int id = blockIdx.x;          // 0..49 = b*25+cs
    int b = id / 25, cs = id - b * 25, c = cs / SS;
    int t = threadIdx.x;          // 384
    __shared__ float sim[PP];
    __shared__ int idxs[KK];
    const float* db = dist + b * (CC * SS * PP);
    if (t < PP) {
        float osum = 0.f;
        for (int cc = 0; cc < CC; ++cc) osum += db[cc * SS * PP + t];   // d0 rows (s=0)
        float other = osum - db[c * SS * PP + t];
        sim[t] = db[cs * PP + t] / (other + 1e-6f);
    }
    __syncthreads();
    for (int j = 0; j < KK; ++j) {
        if (t < 64) {
            float bv = -3.4e38f; int bi = 1 << 30;
            for (int p = t; p < PP; p += 64) {
                float v = sim[p];
                if (v > bv || (v == bv && p < bi)) { bv = v; bi = p; }
            }
#pragma unroll
            for (int off = 1; off < 64; off <<= 1) {
                float ov = __shfl_xor(bv, off); int oi = __shfl_xor(bi, off);
                if (ov > bv || (ov == bv && oi < bi)) { bv = ov; bi = oi; }
            }
            if (t == 0) { idxs[j] = bi; sim[bi] = -3.4e38f; }
        }
        __syncthreads();
    }
    const float* patch = b ? dpfP : epsP;
    const float* cls = b ? dsupC : supC;
    float sum = 0.f;
    for (int j = 0; j < KK; ++j) sum += patch[((size_t)cs * PP + idxs[j]) * DD + t];
    enh[(size_t)id * DD + t] = 2.f * cls[(size_t)cs * DD + t] + sum * (1.f / 30.f);
}

// ---- ep[c] = mean over 10 enh rows; also prototype norms ----
__global__ void ep_k(const float* __restrict__ enh, float* __restrict__ outEp,
                     float* __restrict__ npb) {
    int t = threadIdx.x;  // 384
    __shared__ float red[DD];
    for (int c = 0; c < CC; ++c) {
        float v = 0.f;
        for (int b = 0; b < 2; ++b)
            for (int s = 0; s < SS; ++s)
                v += enh[((b * 25) + (c * SS + s)) * DD + t];
        v *= 0.1f;
        outEp[c * DD + t] = v;
        red[t] = v * v;
        __syncthreads();
        if (t < 64) {
            float s = 0.f;
            for (int i = t; i < DD; i += 64) s += red[i];
#pragma unroll
            for (int off = 32; off > 0; off >>= 1) s += __shfl_xor(s, off);
            if (t == 0) npb[c] = sqrtf(s);
        }
        __syncthreads();
    }
}

// ---- cos[c][q*196+p]: one wave per patch row, coalesced float4 reads ----
__global__ void cos_k(const float* __restrict__ epq, const float* __restrict__ ep,
                      const float* __restrict__ npb, float* __restrict__ cosB) {
    __shared__ __align__(16) float epl[CC * DD];
    __shared__ float npl[CC];
    int t = threadIdx.x;  // 256
    for (int i = t; i < CC * DD; i += 256) epl[i] = ep[i];
    if (t < CC) npl[t] = npb[t];
    __syncthreads();
    int wid = t >> 6, l = t & 63;
    int row = blockIdx.x * 4 + wid;           // 3675*4 = 14700 exactly
    const float4* rp = (const float4*)(epq + (size_t)row * DD);
    const float4* e4 = (const float4*)epl;
    float nq = 0.f, dot[CC];
#pragma unroll
    for (int c = 0; c < CC; ++c) dot[c] = 0.f;
    for (int c4 = l; c4 < DD / 4; c4 += 64) {
        float4 x = rp[c4];
        nq += x.x * x.x + x.y * x.y + x.z * x.z + x.w * x.w;
#pragma unroll
        for (int c = 0; c < CC; ++c) {
            float4 e = e4[c * (DD / 4) + c4];
            dot[c] += e.x * x.x + e.y * x.y + e.z * x.z + e.w * x.w;
        }
    }
#pragma unroll
    for (int off = 32; off > 0; off >>= 1) {
        nq += __shfl_xor(nq, off);
#pragma unroll
        for (int c = 0; c < CC; ++c) dot[c] += __shfl_xor(dot[c], off);
    }
    if (l == 0) {
        float sq = sqrtf(nq);
#pragma unroll
        for (int c = 0; c < CC; ++c)
            cosB[c * QP + row] = dot[c] / fmaxf(npl[c] * sq, 1e-8f);
    }
}

// ---- per-(c,q): softmax over p, top-30, weighted sum gather ----
__global__ void walk2_k(const float* __restrict__ cosB, const float* __restrict__ epq,
                        const float* __restrict__ qcls, float* __restrict__ outp) {
    int bid = blockIdx.x;         // c*75+q
    int c = bid / QQ, q = bid - c * QQ;
    int t = threadIdx.x;          // 256
    __shared__ float red[256];
    __shared__ float wv[PP];
    __shared__ float vals[KK];
    __shared__ int idxs[KK];
    float cosv = -3.4e38f;
    if (t < PP) cosv = cosB[c * QP + q * PP + t];
    red[t] = cosv; __syncthreads();
    for (int st = 128; st > 0; st >>= 1) { if (t < st) red[t] = fmaxf(red[t], red[t + st]); __syncthreads(); }
    float mx = red[0]; __syncthreads();
    float e = (t < PP) ? expf(cosv - mx) : 0.f;
    red[t] = e; __syncthreads();
    for (int st = 128; st > 0; st >>= 1) { if (t < st) red[t] += red[t + st]; __syncthreads(); }
    float inv = 1.f / red[0];
    __syncthreads();
    if (t < PP) wv[t] = e * inv;
    __syncthreads();
    for (int j = 0; j < KK; ++j) {
        if (t < 64) {
            float bv = -3.4e38f; int bi = 1 << 30;
            for (int p = t; p < PP; p += 64) {
                float v = wv[p];
                if (v > bv || (v == bv && p < bi)) { bv = v; bi = p; }
            }
#pragma unroll
            for (int off = 1; off < 64; off <<= 1) {
                float ov = __shfl_xor(bv, off); int oi = __shfl_xor(bi, off);
                if (ov > bv || (ov == bv && oi < bi)) { bv = ov; bi = oi; }
            }
            if (t == 0) { vals[j] = bv; idxs[j] = bi; wv[bi] = -3.4e38f; }
        }
        __syncthreads();
    }
    for (int d = t; d < DD; d += 256) {
        float a = 0.f;
        for (int j = 0; j < KK; ++j) a += vals[j] * epq[((size_t)q * PP + idxs[j]) * DD + d];
        outp[(size_t)bid * DD + d] = 2.f * qcls[q * DD + d] + a;
    }
}

extern "C" void kernel_launch(void* const* d_in, const int* in_sizes, int n_in,
                              void* d_out, int out_size, void* d_ws, size_t ws_size,
                              hipStream_t stream) {
    const float* sup   = (const float*)d_in[0];
    const float* qcls  = (const float*)d_in[1];
    const float* dsupI = (const float*)d_in[2];
    const float* epsI  = (const float*)d_in[3];
    const float* epqI  = (const float*)d_in[4];
    const float* dpI   = (const float*)d_in[5];
    const float* daW1 = (const float*)d_in[6],  *daG1 = (const float*)d_in[8],
               * daBe1 = (const float*)d_in[9], *daAl = (const float*)d_in[10];
    const float* daW2 = (const float*)d_in[11], *daG2 = (const float*)d_in[13],
               * daBe2 = (const float*)d_in[14];
    const float* paW1 = (const float*)d_in[15], *paG1 = (const float*)d_in[17],
               * paBe1 = (const float*)d_in[18], *paAl = (const float*)d_in[19];
    const float* paW2 = (const float*)d_in[20], *paG2 = (const float*)d_in[22],
               * paBe2 = (const float*)d_in[23];

    char* ws = (char*)d_ws;
    size_t off = 0;
    auto alloc = [&](size_t b) -> void* {
        void* p = ws + off;
        off = (off + b + 255) & ~(size_t)255;
        return p;
    };
    // padded row counts (128-aligned so GEMM blocks stay within one segment)
    const int MP_S = 128;                 // dalle_sup: 25 valid
    const int M_P = 4900,  MP_P = 4992;   // patch batches
    const int M_Q = 14700, MP_Q = 14720;  // hmm: 14720 not 128-mult; use 14848
    (void)MP_Q;
    const int MP_Qa = 14848;              // 116*128
    const int ROWS_A = MP_S + MP_P;       // 5120
    const int ROWS_B = MP_P + MP_Qa;      // 19840
    const int ROWS_C = MP_P;              // 4992

    unsigned short* wtAll = (unsigned short*)alloc((size_t)4 * DD * DD * 2);
    unsigned short* wtDa1 = wtAll;
    unsigned short* wtDa2 = wtAll + DD * DD;
    unsigned short* wtPa1 = wtAll + 2 * DD * DD;
    unsigned short* wtPa2 = wtAll + 3 * DD * DD;
    unsigned short* xb    = (unsigned short*)alloc((size_t)ROWS_B * DD * 2);
    float*          hbuf  = (float*)alloc((size_t)ROWS_B * DD * 4);
    unsigned short* a2buf = (unsigned short*)alloc((size_t)ROWS_B * DD * 2);
    float*          partial = (float*)alloc((size_t)(ROWS_B / 128) * DD * 2 * 4);
    float*          mstats  = (float*)alloc(2 * 768 * 4);
    float*          dalleSup = (float*)alloc((size_t)MP_S * DD * 4);
    float*          dp0   = (float*)alloc((size_t)MP_P * DD * 4);
    unsigned short* dp0b  = (unsigned short*)alloc((size_t)MP_P * DD * 2);
    float*          epsB  = (float*)alloc((size_t)MP_P * DD * 4);
    float*          epqB  = (float*)alloc((size_t)MP_Qa * DD * 4);
    float*          dpfB  = (float*)alloc((size_t)MP_P * DD * 4);
    float*          distB = (float*)alloc((size_t)2 * CC * SS * PP * 4);
    float*          enhB  = (float*)alloc((size_t)50 * DD * 4);
    float*          npB   = (float*)alloc(64);
    float*          cosB  = (float*)alloc((size_t)CC * QP * 4);

    // weights -> bf16 transposed (one launch)
    prep_w4<<<4 * 576, 256, 0, stream>>>(daW1, daW2, paW1, paW2, wtAll);

    // ---------- pass A (da): seg0 = dalle_emb_support(25), seg1 = dalle_patch(4900) ----------
    {
        int rows = ROWS_A, nel = rows * DD, mb = rows / 128;
        SegDesc s0{0, 1, 1.f / 25.f}, s1{1, mb, 1.f / 4900.f};
        conv2_k<<<nel / 256, 256, 0, stream>>>(dsupI, 25, MP_S, dpI, M_P, xb);
        gemm_k<<<dim3(mb, 3), 256, 0, stream>>>(xb, wtDa1, hbuf, partial);
        colfin<<<2, 384, 0, stream>>>(partial, s0, s1, mstats);
        act_k<<<nel / 256, 256, 0, stream>>>(hbuf, mstats, daG1, daBe1, daAl, a2buf, MP_S, 25, M_P);
        gemm_k<<<dim3(mb, 3), 256, 0, stream>>>(a2buf, wtDa2, hbuf, partial);
        colfin<<<2, 384, 0, stream>>>(partial, s0, s1, mstats);
        mlp_out_k<<<nel / 256, 256, 0, stream>>>(hbuf, mstats, daG2, daBe2,
                                                 nullptr, dalleSup, nullptr,
                                                 nullptr, dp0, MP_S, 25, M_P);
        // note: seg1 f32 out is dp0; need bf16 copy too -> reuse act-style pass? No:
        // dp0b produced below via conv2 on dp0 (cheap, and keeps out kernel simple).
    }
    // dp0 -> bf16 for pass C input
    conv2_k<<<(ROWS_C * DD) / 256, 256, 0, stream>>>(dp0, M_P, ROWS_C, nullptr, 0, dp0b);

    // ---------- pass B (pa): seg0 = emb_patch_support(4900), seg1 = emb_patch_query(14700) ----------
    {
        int rows = ROWS_B, nel = rows * DD, mb = rows / 128;     // mb = 155
        SegDesc s0{0, MP_P / 128, 1.f / 4900.f}, s1{MP_P / 128, mb, 1.f / 14700.f};
        conv2_k<<<nel / 256, 256, 0, stream>>>(epsI, M_P, MP_P, epqI, M_Q, xb);
        gemm_k<<<dim3(mb, 3), 256, 0, stream>>>(xb, wtPa1, hbuf, partial);
        colfin<<<2, 384, 0, stream>>>(partial, s0, s1, mstats);
        act_k<<<nel / 256, 256, 0, stream>>>(hbuf, mstats, paG1, paBe1, paAl, a2buf, MP_P, M_P, M_Q);
        gemm_k<<<dim3(mb, 3), 256, 0, stream>>>(a2buf, wtPa2, hbuf, partial);
        colfin<<<2, 384, 0, stream>>>(partial, s0, s1, mstats);
        mlp_out_k<<<nel / 256, 256, 0, stream>>>(hbuf, mstats, paG2, paBe2,
                                                 epsI, epsB, nullptr,
                                                 epqI, epqB, MP_P, M_P, M_Q);
    }

    // ---------- pass C (pa on dp0): single segment 4900 ----------
    {
        int rows = ROWS_C, nel = rows * DD, mb = rows / 128;     // mb = 39
        SegDesc s0{0, mb, 1.f / 4900.f}, s1{0, 0, 0.f};
        gemm_k<<<dim3(mb, 3), 256, 0, stream>>>(dp0b, wtPa1, hbuf, partial);
        colfin<<<1, 384, 0, stream>>>(partial, s0, s1, mstats);
        act_k<<<nel / 256, 256, 0, stream>>>(hbuf, mstats, paG1, paBe1, paAl, a2buf, rows, M_P, 0);
        gemm_k<<<dim3(mb, 3), 256, 0, stream>>>(a2buf, wtPa2, hbuf, partial);
        colfin<<<1, 384, 0, stream>>>(partial, s0, s1, mstats);
        mlp_out_k<<<nel / 256, 256, 0, stream>>>(hbuf, mstats, paG2, paBe2,
                                                 dp0, dpfB, nullptr,
                                                 nullptr, dpfB, rows, M_P, 0);
    }

    // ---------- enhancement ----------
    dist_k<<<2 * CC * SS * PP, 64, 0, stream>>>(epsB, dpfB, sup, dalleSup, distB);
    enh_k<<<2 * CC * SS, 384, 0, stream>>>(distB, epsB, dpfB, sup, dalleSup, enhB);

    float* outEp = (float*)d_out;
    float* outW = (float*)d_out + CC * DD;
    ep_k<<<1, 384, 0, stream>>>(enhB, outEp, npB);

    // ---------- feature walk ----------
    cos_k<<<QP / 4, 256, 0, stream>>>(epqB, outEp, npB, cosB);
    walk2_k<<<CC * QQ, 256, 0, stream>>>(cosB, epqB, qcls, outW);
}

// Round 4
// 250.529 us; speedup vs baseline: 2.9655x; 1.4630x over previous
//
#include <hip/hip_runtime.h>

// EnhanceCls: 2 segmented MLP passes (GEMM+fused BN-stats, bf16 H chain) +
// prototype enhancement + feature walk (rank-based top-k, no serial argmax).
// C=5 S=5 Q=75 P=196 D=384 K=30.

#define CC 5
#define SS 5
#define QQ 75
#define PP 196
#define DD 384
#define KK 30
#define QP (QQ * PP)   // 14700

typedef short bf16x8 __attribute__((ext_vector_type(8)));
typedef float f32x4  __attribute__((ext_vector_type(4)));
typedef unsigned short us16x4 __attribute__((ext_vector_type(4)));
typedef unsigned short u16;

struct SegDesc { int b0, b1; float invM; };

__device__ __forceinline__ u16 f2bf(float f) {
    unsigned u = __float_as_uint(f);
    unsigned r = (u + 0x7fffu + ((u >> 16) & 1u)) >> 16;
    return (u16)r;
}
__device__ __forceinline__ float bf2f(u16 h) {
    return __uint_as_float((unsigned)h << 16);
}

__device__ __forceinline__ void lds_load16(const u16* g, u16* s) {
    __builtin_amdgcn_global_load_lds(
        (const __attribute__((address_space(1))) unsigned int*)g,
        (__attribute__((address_space(3))) unsigned int*)s, 16, 0, 0);
}

// ---- weight prep: 4 matrices, Wt[m][n*384+k] = bf16(W[m][k*384+n]) ----
__global__ void prep_w4(const float* __restrict__ W0, const float* __restrict__ W1,
                        const float* __restrict__ W2, const float* __restrict__ W3,
                        u16* __restrict__ Wt) {
    int idx = blockIdx.x * 256 + threadIdx.x;      // 4 * 147456
    int m = idx / (DD * DD);
    int rem = idx - m * (DD * DD);
    int n = rem / DD, k = rem - n * DD;
    const float* W = (m == 0) ? W0 : (m == 1) ? W1 : (m == 2) ? W2 : W3;
    Wt[idx] = f2bf(W[k * DD + n]);
}

// ---- 2-segment f32 -> bf16 (4-wide) with zero row padding ----
__global__ void conv2_k(const float* __restrict__ src0, int M0, int rp0,
                        const float* __restrict__ src1, int M1,
                        u16* __restrict__ dst) {
    int idx4 = blockIdx.x * 256 + threadIdx.x;
    int row = idx4 / 96, cq = idx4 - row * 96;
    f32x4 v = {0.f, 0.f, 0.f, 0.f};
    if (row < rp0) {
        if (row < M0) v = ((const f32x4*)src0)[(size_t)row * 96 + cq];
    } else {
        int r1 = row - rp0;
        if (r1 < M1) v = ((const f32x4*)src1)[(size_t)r1 * 96 + cq];
    }
    us16x4 o;
    o.x = f2bf(v.x); o.y = f2bf(v.y); o.z = f2bf(v.z); o.w = f2bf(v.w);
    ((us16x4*)dst)[idx4] = o;
}

// ---- bf16 GEMM: H(bf16)[Mpad x 384] = A * B (Bt = B^T), fused col-stats ----
__global__ __launch_bounds__(256) void gemm_k(const u16* __restrict__ A,
                                              const u16* __restrict__ Bt,
                                              u16* __restrict__ H,
                                              float* __restrict__ partial) {
    __shared__ __align__(16) u16 As[128 * 64];
    __shared__ __align__(16) u16 Bs[128 * 64];
    __shared__ float sred[2][2][64][2];
    const int tid = threadIdx.x;
    const int w = tid >> 6, l = tid & 63;
    const int wr = w >> 1, wc = w & 1;
    const int m0 = blockIdx.x * 128, n0 = blockIdx.y * 128;

    f32x4 acc[4][4];
#pragma unroll
    for (int i = 0; i < 4; ++i)
#pragma unroll
        for (int j = 0; j < 4; ++j) acc[i][j] = f32x4{0.f, 0.f, 0.f, 0.f};

    int rowg[4], kpg[4];
#pragma unroll
    for (int i = 0; i < 4; ++i) {
        int c = (i * 4096 + w * 1024 + l * 16) >> 4;  // 16B chunk index
        int row = c >> 3, kp = c & 7;
        rowg[i] = row;
        kpg[i] = kp ^ (row & 7);   // pre-swizzled global chunk (both-sides rule)
    }

    for (int kt = 0; kt < 6; ++kt) {
        const int k0 = kt * 64;
#pragma unroll
        for (int i = 0; i < 4; ++i) {
            lds_load16(A  + (size_t)(m0 + rowg[i]) * DD + k0 + kpg[i] * 8, &As[i * 2048 + w * 512]);
            lds_load16(Bt + (size_t)(n0 + rowg[i]) * DD + k0 + kpg[i] * 8, &Bs[i * 2048 + w * 512]);
        }
        __syncthreads();
#pragma unroll
        for (int ks = 0; ks < 2; ++ks) {
            bf16x8 af[4], bg[4];
#pragma unroll
            for (int i = 0; i < 4; ++i) {
                int rm = wr * 64 + i * 16 + (l & 15);
                af[i] = *(const bf16x8*)&As[rm * 64 + (((ks << 2) + (l >> 4)) ^ (rm & 7)) * 8];
                int rn = wc * 64 + i * 16 + (l & 15);
                bg[i] = *(const bf16x8*)&Bs[rn * 64 + (((ks << 2) + (l >> 4)) ^ (rn & 7)) * 8];
            }
#pragma unroll
            for (int i = 0; i < 4; ++i)
#pragma unroll
                for (int j = 0; j < 4; ++j)
                    acc[i][j] = __builtin_amdgcn_mfma_f32_16x16x32_bf16(af[i], bg[j], acc[i][j], 0, 0, 0);
        }
        __syncthreads();
    }
    // C/D layout: col = lane&15, row = (lane>>4)*4 + reg
#pragma unroll
    for (int i = 0; i < 4; ++i) {
        int rb = m0 + wr * 64 + i * 16 + ((l >> 4) << 2);
#pragma unroll
        for (int j = 0; j < 4; ++j) {
            int col = n0 + wc * 64 + j * 16 + (l & 15);
#pragma unroll
            for (int r = 0; r < 4; ++r)
                H[(size_t)(rb + r) * DD + col] = f2bf(acc[i][j][r]);
        }
    }
    // fused column stats (from f32 acc) over this block's 128 rows
    float ls[4], ls2[4];
#pragma unroll
    for (int j = 0; j < 4; ++j) { ls[j] = 0.f; ls2[j] = 0.f; }
#pragma unroll
    for (int i = 0; i < 4; ++i)
#pragma unroll
        for (int j = 0; j < 4; ++j)
#pragma unroll
            for (int r = 0; r < 4; ++r) {
                float v = acc[i][j][r];
                ls[j] += v; ls2[j] += v * v;
            }
#pragma unroll
    for (int j = 0; j < 4; ++j) {
        ls[j]  += __shfl_xor(ls[j], 16);  ls[j]  += __shfl_xor(ls[j], 32);
        ls2[j] += __shfl_xor(ls2[j], 16); ls2[j] += __shfl_xor(ls2[j], 32);
    }
    if ((l >> 4) == 0) {
#pragma unroll
        for (int j = 0; j < 4; ++j) {
            sred[wr][wc][j * 16 + (l & 15)][0] = ls[j];
            sred[wr][wc][j * 16 + (l & 15)][1] = ls2[j];
        }
    }
    __syncthreads();
    if (tid < 128) {
        int wcx = tid >> 6, c64 = tid & 63;
        float sa  = sred[0][wcx][c64][0] + sred[1][wcx][c64][0];
        float sb = sred[0][wcx][c64][1] + sred[1][wcx][c64][1];
        size_t pi = ((size_t)blockIdx.x * DD + n0 + tid) * 2;
        partial[pi] = sa; partial[pi + 1] = sb;
    }
}

// ---- stats finalize: grid = nseg blocks x 384 threads ----
__global__ void colfin(const float* __restrict__ partial, SegDesc s0, SegDesc s1,
                       SegDesc s2, float* __restrict__ mstats) {
    SegDesc sd = (blockIdx.x == 0) ? s0 : (blockIdx.x == 1) ? s1 : s2;
    int t = threadIdx.x;  // 384
    float sa = 0.f, sb = 0.f;
    for (int b = sd.b0; b < sd.b1; ++b) {
        size_t pi = ((size_t)b * DD + t) * 2;
        sa += partial[pi]; sb += partial[pi + 1];
    }
    float m = sa * sd.invM;
    float var = fmaxf(sb * sd.invM - m * m, 0.f);
    mstats[blockIdx.x * 768 + t] = m;
    mstats[blockIdx.x * 768 + 384 + t] = rsqrtf(var + 1e-5f);
}

// ---- BN + leaky-relu -> bf16 (4-wide, up to 3 segments, pad rows -> 0) ----
__global__ void act_k(const u16* __restrict__ H, const float* __restrict__ mstats,
                      const float* __restrict__ g, const float* __restrict__ be,
                      const float* __restrict__ alp, u16* __restrict__ A2,
                      int rb0, int rb1, int M0, int M1, int M2) {
    int idx4 = blockIdx.x * 256 + threadIdx.x;
    int row = idx4 / 96, cq = idx4 - row * 96, col = cq * 4;
    int seg = (row >= rb0) + (row >= rb1);
    int vr = row - (seg == 1 ? rb0 : seg == 2 ? rb1 : 0);
    int M = seg == 0 ? M0 : seg == 1 ? M1 : M2;
    us16x4 o = {0, 0, 0, 0};
    if (vr < M) {
        us16x4 h = ((const us16x4*)H)[idx4];
        const float* ms = mstats + seg * 768;
        f32x4 mm = *(const f32x4*)(ms + col);
        f32x4 iv = *(const f32x4*)(ms + 384 + col);
        f32x4 gg = *(const f32x4*)(g + col);
        f32x4 bb = *(const f32x4*)(be + col);
        float al = *alp;
        float v0 = (bf2f(h.x) - mm.x) * iv.x * gg.x + bb.x; v0 = v0 >= 0.f ? v0 : al * v0;
        float v1 = (bf2f(h.y) - mm.y) * iv.y * gg.y + bb.y; v1 = v1 >= 0.f ? v1 : al * v1;
        float v2 = (bf2f(h.z) - mm.z) * iv.z * gg.z + bb.z; v2 = v2 >= 0.f ? v2 : al * v2;
        float v3 = (bf2f(h.w) - mm.w) * iv.w * gg.w + bb.w; v3 = v3 >= 0.f ? v3 : al * v3;
        o.x = f2bf(v0); o.y = f2bf(v1); o.z = f2bf(v2); o.w = f2bf(v3);
    }
    ((us16x4*)A2)[idx4] = o;
}

// ---- final BN (+res) per segment -> f32 out (+ optional bf16 out), 4-wide ----
__global__ void mlp_out_k(const u16* __restrict__ H, const float* __restrict__ mstats,
                          const float* __restrict__ g, const float* __restrict__ be,
                          const float* __restrict__ res0, float* __restrict__ out0, u16* __restrict__ out0b,
                          const float* __restrict__ res1, float* __restrict__ out1, u16* __restrict__ out1b,
                          const float* __restrict__ res2, float* __restrict__ out2,
                          int rb0, int rb1, int M0, int M1, int M2) {
    int idx4 = blockIdx.x * 256 + threadIdx.x;
    int row = idx4 / 96, cq = idx4 - row * 96, col = cq * 4;
    int seg = (row >= rb0) + (row >= rb1);
    int vr = row - (seg == 1 ? rb0 : seg == 2 ? rb1 : 0);
    int M = seg == 0 ? M0 : seg == 1 ? M1 : M2;
    const float* res = seg == 0 ? res0 : seg == 1 ? res1 : res2;
    float* outf = seg == 0 ? out0 : seg == 1 ? out1 : out2;
    u16* outb = seg == 0 ? out0b : seg == 1 ? out1b : (u16*)nullptr;
    f32x4 v = {0.f, 0.f, 0.f, 0.f};
    if (vr < M) {
        us16x4 h = ((const us16x4*)H)[idx4];
        const float* ms = mstats + seg * 768;
        f32x4 mm = *(const f32x4*)(ms + col);
        f32x4 iv = *(const f32x4*)(ms + 384 + col);
        f32x4 gg = *(const f32x4*)(g + col);
        f32x4 bb = *(const f32x4*)(be + col);
        v.x = (bf2f(h.x) - mm.x) * iv.x * gg.x + bb.x;
        v.y = (bf2f(h.y) - mm.y) * iv.y * gg.y + bb.y;
        v.z = (bf2f(h.z) - mm.z) * iv.z * gg.z + bb.z;
        v.w = (bf2f(h.w) - mm.w) * iv.w * gg.w + bb.w;
        if (res) {
            f32x4 r = ((const f32x4*)res)[(size_t)vr * 96 + cq];
            v.x += r.x; v.y += r.y; v.z += r.z; v.w += r.w;
        }
    }
    size_t oi = (size_t)vr * 96 + cq;
    ((f32x4*)outf)[oi] = v;
    if (outb) {
        us16x4 o;
        o.x = f2bf(v.x); o.y = f2bf(v.y); o.z = f2bf(v.z); o.w = f2bf(v.w);
        ((us16x4*)outb)[oi] = o;
    }
}

// ---- dist[b][cs][p] = ||cls[cs]-patch[cs,p]||  (1 wave per row) ----
__global__ void dist_k(const float* __restrict__ epsP, const float* __restrict__ dpfP,
                       const float* __restrict__ supC, const float* __restrict__ dsupC,
                       float* __restrict__ dist) {
    int id = blockIdx.x;               // 0..9799
    int b = id / (CC * SS * PP);
    int r = id - b * (CC * SS * PP);   // cs*196+p
    int cs = r / PP;
    const float* patch = b ? dpfP : epsP;
    const float* cls = b ? dsupC : supC;
    int l = threadIdx.x;  // 64
    const float* pr = patch + (size_t)r * DD;
    const float* cr = cls + (size_t)cs * DD;
    float s = 0.f;
    for (int d = l; d < DD; d += 64) { float df = cr[d] - pr[d]; s += df * df; }
#pragma unroll
    for (int off = 32; off > 0; off >>= 1) s += __shfl_xor(s, off);
    if (l == 0) dist[id] = sqrtf(s);
}

// ---- enhance: sim = dist/(other+1e-6), rank-based top-30, mean of selected ----
__global__ void enh_k(const float* __restrict__ dist, const float* __restrict__ epsP,
                      const float* __restrict__ dpfP, const float* __restrict__ supC,
                      const float* __restrict__ dsupC, float* __restrict__ enh) {
    int id = blockIdx.x;          // 0..49 = b*25+cs
    int b = id / 25, cs = id - b * 25, c = cs / SS;
    int t = threadIdx.x;          // 384
    __shared__ float sim[PP];
    __shared__ int sidx[KK];
    const float* db = dist + b * (CC * SS * PP);
    if (t < PP) {
        float osum = 0.f;
        for (int cc = 0; cc < CC; ++cc) osum += db[cc * SS * PP + t];   // d0 (s=0) rows
        float other = osum - db[c * SS * PP + t];
        sim[t] = db[cs * PP + t] / (other + 1e-6f);
    }
    __syncthreads();
    if (t < PP) {
        float mine = sim[t];
        int cnt = 0;
        for (int p = 0; p < PP; ++p) {
            float v = sim[p];
            cnt += (v > mine) || (v == mine && p < t);
        }
        if (cnt < KK) sidx[cnt] = t;     // rank unique -> no race
    }
    __syncthreads();
    const float* patch = b ? dpfP : epsP;
    const float* cls = b ? dsupC : supC;
    float sum = 0.f;
#pragma unroll
    for (int j = 0; j < KK; ++j) sum += patch[((size_t)cs * PP + sidx[j]) * DD + t];
    enh[(size_t)id * DD + t] = 2.f * cls[(size_t)cs * DD + t] + sum * (1.f / 30.f);
}

// ---- ep[c] = mean over 10 enh rows; also prototype norms ----
__global__ void ep_k(const float* __restrict__ enh, float* __restrict__ outEp,
                     float* __restrict__ npb) {
    int t = threadIdx.x;  // 384
    __shared__ float red[DD];
    for (int c = 0; c < CC; ++c) {
        float v = 0.f;
        for (int b = 0; b < 2; ++b)
            for (int s = 0; s < SS; ++s)
                v += enh[((b * 25) + (c * SS + s)) * DD + t];
        v *= 0.1f;
        outEp[c * DD + t] = v;
        red[t] = v * v;
        __syncthreads();
        if (t < 64) {
            float s = 0.f;
            for (int i = t; i < DD; i += 64) s += red[i];
#pragma unroll
            for (int off = 32; off > 0; off >>= 1) s += __shfl_xor(s, off);
            if (t == 0) npb[c] = sqrtf(s);
        }
        __syncthreads();
    }
}

// ---- eB[c][row] = exp(cos(proto_c, patch_row) - 1): coalesced float4 reads ----
// (softmax shift by constant 1 instead of row max: cos <= 1, identical after norm)
__global__ void cos_k(const float* __restrict__ epq, const float* __restrict__ ep,
                      const float* __restrict__ npb, float* __restrict__ eB) {
    __shared__ __align__(16) float epl[CC * DD];
    __shared__ float npl[CC];
    int t = threadIdx.x;  // 256
    for (int i = t; i < CC * DD; i += 256) epl[i] = ep[i];
    if (t < CC) npl[t] = npb[t];
    __syncthreads();
    int wid = t >> 6, l = t & 63;
    int row = blockIdx.x * 4 + wid;           // 3675*4 = 14700 exactly
    const float4* rp = (const float4*)(epq + (size_t)row * DD);
    const float4* e4 = (const float4*)epl;
    float nq = 0.f, dot[CC];
#pragma unroll
    for (int c = 0; c < CC; ++c) dot[c] = 0.f;
    for (int c4 = l; c4 < DD / 4; c4 += 64) {
        float4 x = rp[c4];
        nq += x.x * x.x + x.y * x.y + x.z * x.z + x.w * x.w;
#pragma unroll
        for (int c = 0; c < CC; ++c) {
            float4 e = e4[c * (DD / 4) + c4];
            dot[c] += e.x * x.x + e.y * x.y + e.z * x.z + e.w * x.w;
        }
    }
#pragma unroll
    for (int off = 32; off > 0; off >>= 1) {
        nq += __shfl_xor(nq, off);
#pragma unroll
        for (int c = 0; c < CC; ++c) dot[c] += __shfl_xor(dot[c], off);
    }
    if (l == 0) {
        float sq = sqrtf(nq);
#pragma unroll
        for (int c = 0; c < CC; ++c)
            eB[c * QP + row] = expf(dot[c] / fmaxf(npl[c] * sq, 1e-8f) - 1.f);
    }
}

// ---- per-(c,q): normalize e, rank-based top-30, weighted-sum gather ----
__global__ void walk2_k(const float* __restrict__ eB, const float* __restrict__ epq,
                        const float* __restrict__ qcls, float* __restrict__ outp) {
    int bid = blockIdx.x;         // c*75+q
    int c = bid / QQ, q = bid - c * QQ;
    int t = threadIdx.x;          // 256
    __shared__ float wv[PP];
    __shared__ float red[256];
    __shared__ float sval[KK];
    __shared__ int sidx[KK];
    float e = 0.f;
    if (t < PP) { e = eB[c * QP + q * PP + t]; wv[t] = e; }
    red[t] = e;
    __syncthreads();
    for (int st = 128; st > 0; st >>= 1) { if (t < st) red[t] += red[t + st]; __syncthreads(); }
    float inv = 1.f / red[0];
    if (t < PP) {
        int cnt = 0;
        for (int p = 0; p < PP; ++p) {
            float v = wv[p];
            cnt += (v > e) || (v == e && p < t);
        }
        if (cnt < KK) { sval[cnt] = e * inv; sidx[cnt] = t; }
    }
    __syncthreads();
    const float* eb = epq + (size_t)q * PP * DD;
    for (int d = t; d < DD; d += 256) {
        float a = 0.f;
#pragma unroll
        for (int j = 0; j < KK; ++j) a += sval[j] * eb[(size_t)sidx[j] * DD + d];
        outp[(size_t)bid * DD + d] = 2.f * qcls[q * DD + d] + a;
    }
}

extern "C" void kernel_launch(void* const* d_in, const int* in_sizes, int n_in,
                              void* d_out, int out_size, void* d_ws, size_t ws_size,
                              hipStream_t stream) {
    const float* sup   = (const float*)d_in[0];
    const float* qcls  = (const float*)d_in[1];
    const float* dsupI = (const float*)d_in[2];
    const float* epsI  = (const float*)d_in[3];
    const float* epqI  = (const float*)d_in[4];
    const float* dpI   = (const float*)d_in[5];
    const float* daW1 = (const float*)d_in[6],  *daG1 = (const float*)d_in[8],
               * daBe1 = (const float*)d_in[9], *daAl = (const float*)d_in[10];
    const float* daW2 = (const float*)d_in[11], *daG2 = (const float*)d_in[13],
               * daBe2 = (const float*)d_in[14];
    const float* paW1 = (const float*)d_in[15], *paG1 = (const float*)d_in[17],
               * paBe1 = (const float*)d_in[18], *paAl = (const float*)d_in[19];
    const float* paW2 = (const float*)d_in[20], *paG2 = (const float*)d_in[22],
               * paBe2 = (const float*)d_in[23];

    char* ws = (char*)d_ws;
    size_t off = 0;
    auto alloc = [&](size_t b) -> void* {
        void* p = ws + off;
        off = (off + b + 255) & ~(size_t)255;
        return p;
    };
    // row geometry (all 128-aligned so GEMM blocks stay within one segment)
    const int MP_S = 128;                  // dalle_sup: 25 valid
    const int M_P = 4900,  MP_P = 4992;    // patch batches
    const int M_Q = 14700, MP_Qa = 14848;  // query patches
    const int ROWS_A  = MP_S + MP_P;               // 5120
    const int ROWS_BC = MP_P + MP_Qa + MP_P;       // 24832
    const int RB0 = MP_P, RB1 = MP_P + MP_Qa;      // 4992, 19840

    u16*   wtAll = (u16*)alloc((size_t)4 * DD * DD * 2);
    u16*   wtDa1 = wtAll;
    u16*   wtDa2 = wtAll + DD * DD;
    u16*   wtPa1 = wtAll + 2 * DD * DD;
    u16*   wtPa2 = wtAll + 3 * DD * DD;
    u16*   xbA   = (u16*)alloc((size_t)ROWS_A * DD * 2);
    u16*   xb    = (u16*)alloc((size_t)ROWS_BC * DD * 2);
    u16*   hbuf  = (u16*)alloc((size_t)ROWS_BC * DD * 2);
    u16*   a2buf = (u16*)alloc((size_t)ROWS_BC * DD * 2);
    float* partial = (float*)alloc((size_t)(ROWS_BC / 128) * DD * 2 * 4);
    float* mstats  = (float*)alloc(3 * 768 * 4);
    float* dalleSup = (float*)alloc((size_t)MP_S * DD * 4);
    float* dp0   = (float*)alloc((size_t)MP_P * DD * 4);
    float* epsB  = (float*)alloc((size_t)MP_P * DD * 4);
    float* epqB  = (float*)alloc((size_t)MP_Qa * DD * 4);
    float* dpfB  = (float*)alloc((size_t)MP_P * DD * 4);
    float* distB = (float*)alloc((size_t)2 * CC * SS * PP * 4);
    float* enhB  = (float*)alloc((size_t)50 * DD * 4);
    float* npB   = (float*)alloc(64);
    float* eB    = (float*)alloc((size_t)CC * QP * 4);

    // weights -> bf16 transposed (one launch)
    prep_w4<<<4 * 576, 256, 0, stream>>>(daW1, daW2, paW1, paW2, wtAll);
    // BC input conversion for segments 0,1 (seg2 written by pass-A output)
    conv2_k<<<(RB1 * 96) / 256, 256, 0, stream>>>(epsI, M_P, MP_P, epqI, M_Q, xb);

    // ---------- pass A (da): seg0 = dalle_emb_support(25), seg1 = dalle_patch(4900) ----------
    {
        int mb = ROWS_A / 128;   // 40
        SegDesc s0{0, 1, 1.f / 25.f}, s1{1, mb, 1.f / 4900.f}, sx{0, 0, 0.f};
        int g96 = (ROWS_A * 96) / 256;   // 1920
        conv2_k<<<g96, 256, 0, stream>>>(dsupI, 25, MP_S, dpI, M_P, xbA);
        gemm_k<<<dim3(mb, 3), 256, 0, stream>>>(xbA, wtDa1, hbuf, partial);
        colfin<<<2, 384, 0, stream>>>(partial, s0, s1, sx, mstats);
        act_k<<<g96, 256, 0, stream>>>(hbuf, mstats, daG1, daBe1, daAl, a2buf,
                                       MP_S, ROWS_A, 25, M_P, 0);
        gemm_k<<<dim3(mb, 3), 256, 0, stream>>>(a2buf, wtDa2, hbuf, partial);
        colfin<<<2, 384, 0, stream>>>(partial, s0, s1, sx, mstats);
        // seg1 writes dp0 (f32) AND the bf16 copy straight into xb segment 2
        mlp_out_k<<<g96, 256, 0, stream>>>(hbuf, mstats, daG2, daBe2,
                                           nullptr, dalleSup, nullptr,
                                           nullptr, dp0, xb + (size_t)RB1 * DD,
                                           nullptr, nullptr,
                                           MP_S, ROWS_A, 25, M_P, 0);
    }

    // ---------- pass BC (pa): seg0 = eps(4900), seg1 = epq(14700), seg2 = dalle_patch(4900) ----------
    {
        int mb = ROWS_BC / 128;  // 194
        SegDesc s0{0, RB0 / 128, 1.f / 4900.f},
                s1{RB0 / 128, RB1 / 128, 1.f / 14700.f},
                s2{RB1 / 128, mb, 1.f / 4900.f};
        int g96 = (ROWS_BC * 96) / 256;  // 9312
        gemm_k<<<dim3(mb, 3), 256, 0, stream>>>(xb, wtPa1, hbuf, partial);
        colfin<<<3, 384, 0, stream>>>(partial, s0, s1, s2, mstats);
        act_k<<<g96, 256, 0, stream>>>(hbuf, mstats, paG1, paBe1, paAl, a2buf,
                                       RB0, RB1, M_P, M_Q, M_P);
        gemm_k<<<dim3(mb, 3), 256, 0, stream>>>(a2buf, wtPa2, hbuf, partial);
        colfin<<<3, 384, 0, stream>>>(partial, s0, s1, s2, mstats);
        mlp_out_k<<<g96, 256, 0, stream>>>(hbuf, mstats, paG2, paBe2,
                                           epsI, epsB, nullptr,
                                           epqI, epqB, nullptr,
                                           dp0, dpfB,
                                           RB0, RB1, M_P, M_Q, M_P);
    }

    // ---------- enhancement ----------
    dist_k<<<2 * CC * SS * PP, 64, 0, stream>>>(epsB, dpfB, sup, dalleSup, distB);
    enh_k<<<2 * CC * SS, 384, 0, stream>>>(distB, epsB, dpfB, sup, dalleSup, enhB);

    float* outEp = (float*)d_out;
    float* outW = (float*)d_out + CC * DD;
    ep_k<<<1, 384, 0, stream>>>(enhB, outEp, npB);

    // ---------- feature walk ----------
    cos_k<<<QP / 4, 256, 0, stream>>>(epqB, outEp, npB, eB);
    walk2_k<<<CC * QQ, 256, 0, stream>>>(eB, epqB, qcls, outW);
}